// Round 13
// baseline (428.288 us; speedup 1.0000x reference)
//
#include <hip/hip_runtime.h>
#include <hip/hip_bf16.h>

// 2-layer GCN on MI355X.
// out[v] = dinv[v] * ( sum_{e: dst=v} g[src_e] + g[v] ) + b,  g = (x@W) * dinv[row]
// dinv[v] = rsqrt(indeg(v) + 1)
// CSR build = bucketed counting sort, ALL atomics in LDS (no device atomics).
// g1/g2 stored BF16. aggregate: r9 version (half-wave pair-gather, 16-deep
// chained pipeline + binary tail) — r10/r11/r12 flat variants all regressed;
// 42 us is the practical floor for 88 MB of cross-XCD duplicated gather traffic.
// GEMM: W in LDS fp32, 4 rows x 8 cols per thread, DEPTH-4 X prefetch
// (r9's 1-deep covered only ~256 issue-cy; L2/HBM misses are 200-900 cy).

#define FDIM 64    // HID_DIM == OUT_DIM
#define NPB  128   // nodes per bucket (dst >> 7)
#define MAXB1 800  // >= ceil(100000/128)=782

// bf16 helpers (bit-level; finite data only)
static __device__ __forceinline__ unsigned short f2bf(float f) {
    unsigned int u = __float_as_uint(f);
    unsigned int r = 0x7FFFu + ((u >> 16) & 1u);
    return (unsigned short)((u + r) >> 16);
}
static __device__ __forceinline__ float lof(unsigned int u) {   // low bf16 -> f32
    return __uint_as_float(u << 16);
}
static __device__ __forceinline__ float hif(unsigned int u) {   // high bf16 -> f32
    return __uint_as_float(u & 0xFFFF0000u);
}

// ---------------- phase 1a: per-block bucket histogram ----------------
__global__ __launch_bounds__(256) void bucket_hist(const int* __restrict__ dst, int E,
                                                   int B1, int chunk, int B0,
                                                   int* __restrict__ H) {
    __shared__ int hist[MAXB1];
    const int blk = blockIdx.x, t = threadIdx.x;
    for (int i = t; i < B1; i += 256) hist[i] = 0;
    __syncthreads();
    const int beg = blk * chunk, end = min(E, beg + chunk);
    for (int e = beg + t; e < end; e += 256) atomicAdd(&hist[dst[e] >> 7], 1);
    __syncthreads();
    for (int i = t; i < B1; i += 256) H[i * B0 + blk] = hist[i];  // bin-major
}

// ---------------- scan A: per-block sums over spans of 2048 ----------------
__global__ __launch_bounds__(256) void scanA(const int* __restrict__ a, int S,
                                             int* __restrict__ bs) {
    __shared__ int s[256];
    const int blk = blockIdx.x, t = threadIdx.x;
    const int base = blk * 2048 + t * 8;
    int sum = 0;
    #pragma unroll
    for (int j = 0; j < 8; ++j) { int idx = base + j; if (idx < S) sum += a[idx]; }
    s[t] = sum;
    __syncthreads();
    for (int off = 128; off > 0; off >>= 1) {
        if (t < off) s[t] += s[t + off];
        __syncthreads();
    }
    if (t == 0) bs[blk] = s[0];
}

// ---------------- scan B: exclusive scan of block sums (nB <= 512) ----------
__global__ __launch_bounds__(512) void scanB(int* __restrict__ bs, int nB) {
    __shared__ int s[512];
    const int t = threadIdx.x;
    int v = (t < nB) ? bs[t] : 0;
    s[t] = v;
    __syncthreads();
    for (int off = 1; off < 512; off <<= 1) {
        int x = s[t];
        int y = (t >= off) ? s[t - off] : 0;
        __syncthreads();
        s[t] = x + y;
        __syncthreads();
    }
    if (t < nB) bs[t] = s[t] - v;
}

// ---------------- scan C: in-place exclusive scan (span 2048/block) ---------
__global__ __launch_bounds__(256) void scanC(int* __restrict__ a, int S,
                                             const int* __restrict__ bs) {
    __shared__ int s[256];
    const int blk = blockIdx.x, t = threadIdx.x;
    const int base = blk * 2048 + t * 8;
    int v[8];
    int sum = 0;
    #pragma unroll
    for (int j = 0; j < 8; ++j) { int idx = base + j; v[j] = (idx < S) ? a[idx] : 0; sum += v[j]; }
    s[t] = sum;
    __syncthreads();
    const int own = sum;
    for (int off = 1; off < 256; off <<= 1) {
        int x = s[t];
        int y = (t >= off) ? s[t - off] : 0;
        __syncthreads();
        s[t] = x + y;
        __syncthreads();
    }
    int run = bs[blk] + s[t] - own;   // exclusive prefix for this thread's segment
    #pragma unroll
    for (int j = 0; j < 8; ++j) { int idx = base + j; if (idx < S) a[idx] = run; run += v[j]; }
}

// ------- phase 1b: scatter edges into bucket-grouped packed (dlow7,src) -----
__global__ __launch_bounds__(256) void bucket_scatter(const int* __restrict__ src,
                                                      const int* __restrict__ dst,
                                                      int E, int B1, int chunk, int B0,
                                                      const int* __restrict__ Hs,
                                                      int* __restrict__ pairs) {
    __shared__ int cur[MAXB1];
    const int blk = blockIdx.x, t = threadIdx.x;
    for (int i = t; i < B1; i += 256) cur[i] = Hs[i * B0 + blk];
    __syncthreads();
    const int beg = blk * chunk, end = min(E, beg + chunk);
    for (int e = beg + t; e < end; e += 256) {
        int d = dst[e];
        int pos = atomicAdd(&cur[d >> 7], 1);          // LDS atomic
        pairs[pos] = ((d & 127) << 17) | src[e];       // src < 2^17
    }
}

// ---------------- phase 2: per-bucket local counting sort -> CSR ------------
__global__ __launch_bounds__(256) void bucket_csr(const int* __restrict__ pairs,
                                                  const int* __restrict__ Hs,
                                                  int B0, int E, int N,
                                                  float* __restrict__ dinv,
                                                  int* __restrict__ rowStart,
                                                  int* __restrict__ srcSorted) {
    __shared__ int hist[NPB], pref[NPB], cur[NPB];
    const int b = blockIdx.x, t = threadIdx.x;
    const int B1 = gridDim.x;
    const int vbase = b * NPB;
    const int nv = min(NPB, N - vbase);
    const int estart = Hs[b * B0];
    const int eend = (b + 1 < B1) ? Hs[(b + 1) * B0] : E;

    if (t < NPB) hist[t] = 0;
    __syncthreads();
    for (int e = estart + t; e < eend; e += 256)
        atomicAdd(&hist[pairs[e] >> 17], 1);
    __syncthreads();

    if (t < NPB) pref[t] = hist[t];
    __syncthreads();
    for (int off = 1; off < NPB; off <<= 1) {
        int v = 0;
        if (t < NPB && t >= off) v = pref[t - off];
        __syncthreads();
        if (t < NPB) pref[t] += v;
        __syncthreads();
    }
    if (t < nv) {
        int ex = pref[t] - hist[t];          // exclusive prefix
        rowStart[vbase + t] = estart + ex;
        dinv[vbase + t] = rsqrtf((float)(hist[t] + 1));
        cur[t] = estart + ex;
    }
    if (b == B1 - 1 && t == 0) rowStart[N] = E;
    __syncthreads();
    for (int e = estart + t; e < eend; e += 256) {
        int p = pairs[e];
        int pos = atomicAdd(&cur[p >> 17], 1);       // LDS atomic
        srcSorted[pos] = p & 0x1FFFF;
    }
}

// ------- GEMM: W in LDS, 4 rows x 8 cols per thread, DEPTH-4 X prefetch -----
// Block = 256 threads, 128 rows/block. Thread t: cq=t&7 (cols 8cq..8cq+7),
// rg=t>>3 (rows 4rg..4rg+3). Queue of 4 k4-slots (16 named float4s); slot i
// reloaded right after its consume -> next use 3 bodies (~768 issue-cy) later.
// launch_bounds(256,3): VGPR cap ~168 (queue 64 + acc 32 + temps); grid 782
// limits occupancy to ~3 waves/SIMD anyway.
template <int K>
__global__ __launch_bounds__(256, 3) void gemm_scale(const float* __restrict__ X,
                                                     const float* __restrict__ W,
                                                     const float* __restrict__ dinv,
                                                     unsigned short* __restrict__ G, int N) {
    __shared__ float Wl[K * FDIM];
    const int t = threadIdx.x;
    {
        const float4* Wv  = reinterpret_cast<const float4*>(W);
        float4*       Wlv = reinterpret_cast<float4*>(Wl);
        #pragma unroll
        for (int i = 0; i < (K * FDIM) / (256 * 4); ++i)
            Wlv[i * 256 + t] = Wv[i * 256 + t];
    }
    __syncthreads();

    const int cq = t & 7;                    // col-group: cols 8cq..8cq+7
    const int rg = t >> 3;                   // row-group: 4 rows
    const int r0 = blockIdx.x * 128 + rg * 4;
    if (r0 >= N) return;                     // no barriers below

    const int rA = r0;
    const int rB = min(r0 + 1, N - 1);
    const int rC = min(r0 + 2, N - 1);
    const int rD = min(r0 + 3, N - 1);
    const float4* xrA = reinterpret_cast<const float4*>(X + (size_t)rA * K);
    const float4* xrB = reinterpret_cast<const float4*>(X + (size_t)rB * K);
    const float4* xrC = reinterpret_cast<const float4*>(X + (size_t)rC * K);
    const float4* xrD = reinterpret_cast<const float4*>(X + (size_t)rD * K);

    float acc[4][8];
    #pragma unroll
    for (int i = 0; i < 4; ++i)
        #pragma unroll
        for (int c = 0; c < 8; ++c) acc[i][c] = 0.f;

    auto do_k4 = [&](int k4, float4 c0, float4 c1, float4 c2, float4 c3) {
        float xs0[4] = {c0.x, c0.y, c0.z, c0.w};
        float xs1[4] = {c1.x, c1.y, c1.z, c1.w};
        float xs2[4] = {c2.x, c2.y, c2.z, c2.w};
        float xs3[4] = {c3.x, c3.y, c3.z, c3.w};
        #pragma unroll
        for (int j = 0; j < 4; ++j) {
            const float4* wp = reinterpret_cast<const float4*>(Wl + (size_t)(4 * k4 + j) * FDIM + cq * 8);
            float4 w0 = wp[0], w1 = wp[1];
            float wv[8] = {w0.x, w0.y, w0.z, w0.w, w1.x, w1.y, w1.z, w1.w};
            #pragma unroll
            for (int c = 0; c < 8; ++c) {
                acc[0][c] += xs0[j] * wv[c];
                acc[1][c] += xs1[j] * wv[c];
                acc[2][c] += xs2[j] * wv[c];
                acc[3][c] += xs3[j] * wv[c];
            }
        }
    };

    // depth-4 software pipeline: 16 named float4s (4 rows x 4 slots)
    // K/4 is 32 (K=128) or 16 (K=64): multiple of 4, main loop ends at K/4-4.
    float4 a0 = xrA[0], b0 = xrB[0], c0 = xrC[0], d0 = xrD[0];
    float4 a1 = xrA[1], b1 = xrB[1], c1 = xrC[1], d1 = xrD[1];
    float4 a2 = xrA[2], b2 = xrB[2], c2 = xrC[2], d2 = xrD[2];
    float4 a3 = xrA[3], b3 = xrB[3], c3 = xrC[3], d3 = xrD[3];

    for (int k4 = 0; k4 < K / 4 - 4; k4 += 4) {
        do_k4(k4 + 0, a0, b0, c0, d0);
        a0 = xrA[k4 + 4]; b0 = xrB[k4 + 4]; c0 = xrC[k4 + 4]; d0 = xrD[k4 + 4];
        do_k4(k4 + 1, a1, b1, c1, d1);
        a1 = xrA[k4 + 5]; b1 = xrB[k4 + 5]; c1 = xrC[k4 + 5]; d1 = xrD[k4 + 5];
        do_k4(k4 + 2, a2, b2, c2, d2);
        a2 = xrA[k4 + 6]; b2 = xrB[k4 + 6]; c2 = xrC[k4 + 6]; d2 = xrD[k4 + 6];
        do_k4(k4 + 3, a3, b3, c3, d3);
        a3 = xrA[k4 + 7]; b3 = xrB[k4 + 7]; c3 = xrC[k4 + 7]; d3 = xrD[k4 + 7];
    }
    // epilogue: consume the last 4 slots (k4 = K/4-4 .. K/4-1)
    do_k4(K / 4 - 4, a0, b0, c0, d0);
    do_k4(K / 4 - 3, a1, b1, c1, d1);
    do_k4(K / 4 - 2, a2, b2, c2, d2);
    do_k4(K / 4 - 1, a3, b3, c3, d3);

    #pragma unroll
    for (int i = 0; i < 4; ++i) {
        const int r = r0 + i;
        if (r < N) {
            const float dv = dinv[r];
            unsigned int p0 = f2bf(acc[i][0] * dv) | (f2bf(acc[i][1] * dv) << 16);
            unsigned int p1 = f2bf(acc[i][2] * dv) | (f2bf(acc[i][3] * dv) << 16);
            unsigned int p2 = f2bf(acc[i][4] * dv) | (f2bf(acc[i][5] * dv) << 16);
            unsigned int p3 = f2bf(acc[i][6] * dv) | (f2bf(acc[i][7] * dv) << 16);
            *reinterpret_cast<uint4*>(G + (size_t)r * FDIM + cq * 8) = make_uint4(p0, p1, p2, p3);
        }
    }
}

// ------- aggregate (r9 version, 42 us): wave/node, half-wave pair-gather,
// 16-deep chained pipeline + binary tail --------------------------------------
#define GATHER2(ii, uu, off)  int ii = srcSorted[eb + 2*(off)]; \
                              unsigned int uu = Gu[(size_t)ii * 32 + fl];

__global__ __launch_bounds__(256, 4) void aggregate(const unsigned int* __restrict__ Gu,
                                                    const int* __restrict__ rowStart,
                                                    const int* __restrict__ srcSorted,
                                                    const float* __restrict__ dinv,
                                                    const float* __restrict__ bias,
                                                    float* __restrict__ OUT, int N, int doRelu) {
    const int lane   = threadIdx.x & 63;
    const int half   = lane >> 5;        // 0: even edges, 1: odd edges
    const int fl     = lane & 31;        // uint index within row (features 2fl,2fl+1)
    const int waveId = blockIdx.x * (blockDim.x >> 6) + (threadIdx.x >> 6);
    const int nWaves = gridDim.x * (blockDim.x >> 6);
    const float2 bv  = reinterpret_cast<const float2*>(bias)[fl];

    for (int v = waveId; v < N; v += nWaves) {
        const int beg = rowStart[v];
        const int end = rowStart[v + 1];

        unsigned int su = 0;
        if (half == 0) su = Gu[(size_t)v * 32 + fl];
        float ax = lof(su), ay = hif(su);

        int e = beg;
        for (; e + 16 <= end; e += 16) {
            const int eb = e + half;
            GATHER2(i0, u0, 0) GATHER2(i1, u1, 1) GATHER2(i2, u2, 2) GATHER2(i3, u3, 3)
            GATHER2(i4, u4, 4) GATHER2(i5, u5, 5) GATHER2(i6, u6, 6) GATHER2(i7, u7, 7)
            ax += ((lof(u0) + lof(u1)) + (lof(u2) + lof(u3)))
                + ((lof(u4) + lof(u5)) + (lof(u6) + lof(u7)));
            ay += ((hif(u0) + hif(u1)) + (hif(u2) + hif(u3)))
                + ((hif(u4) + hif(u5)) + (hif(u6) + hif(u7)));
        }
        int rem = end - e;
        if (rem >= 8) {
            const int eb = e + half;
            GATHER2(i0, u0, 0) GATHER2(i1, u1, 1) GATHER2(i2, u2, 2) GATHER2(i3, u3, 3)
            ax += (lof(u0) + lof(u1)) + (lof(u2) + lof(u3));
            ay += (hif(u0) + hif(u1)) + (hif(u2) + hif(u3));
            e += 8; rem -= 8;
        }
        if (rem >= 4) {
            const int eb = e + half;
            GATHER2(i0, u0, 0) GATHER2(i1, u1, 1)
            ax += lof(u0) + lof(u1);
            ay += hif(u0) + hif(u1);
            e += 4; rem -= 4;
        }
        if (rem >= 2) {
            const int eb = e + half;
            GATHER2(i0, u0, 0)
            ax += lof(u0);
            ay += hif(u0);
            e += 2; rem -= 2;
        }
        if (rem) {
            int i0 = srcSorted[e];
            unsigned int u0 = 0;
            if (half == 0) u0 = Gu[(size_t)i0 * 32 + fl];
            ax += lof(u0);
            ay += hif(u0);
        }

        ax += __shfl_xor(ax, 32, 64);
        ay += __shfl_xor(ay, 32, 64);

        const float dv = dinv[v];
        float2 r;
        r.x = ax * dv + bv.x;
        r.y = ay * dv + bv.y;
        if (doRelu) { r.x = fmaxf(r.x, 0.f); r.y = fmaxf(r.y, 0.f); }
        if (half == 0)
            reinterpret_cast<float2*>(OUT + (size_t)v * FDIM)[fl] = r;
    }
}

extern "C" void kernel_launch(void* const* d_in, const int* in_sizes, int n_in,
                              void* d_out, int out_size, void* d_ws, size_t ws_size,
                              hipStream_t stream) {
    const float* x     = (const float*)d_in[0];
    const int*   edges = (const int*)d_in[1];   // int32 per harness contract
    const float* W1    = (const float*)d_in[2];
    const float* b1    = (const float*)d_in[3];
    const float* W2    = (const float*)d_in[4];
    const float* b2    = (const float*)d_in[5];
    float*       out   = (float*)d_out;

    const int N = in_sizes[0] / 128;   // 100000
    const int E = in_sizes[1] / 2;     // 1600000
    const int* srcIdx = edges;
    const int* dstIdx = edges + E;

    const int B1 = (N + NPB - 1) / NPB;         // 782 buckets
    const int B0 = 256;                          // phase-1 blocks
    const int chunk = (E + B0 - 1) / B0;         // 6250
    const int S  = B1 * B0;                      // scanned size (200192)
    const int nSB = (S + 2047) / 2048;           // 98 scan blocks (<=512)

    // workspace layout (256B aligned slices)
    char* ws = (char*)d_ws;
    size_t off = 0;
    auto alloc = [&](size_t bytes) { char* p = ws + off; off = (off + bytes + 255) & ~(size_t)255; return p; };
    float* dinv      = (float*)alloc((size_t)N * 4);
    int*   H         = (int*)  alloc((size_t)S * 4);
    int*   blockSums = (int*)  alloc(512 * 4);
    int*   rowStart  = (int*)  alloc((size_t)(N + 1) * 4);
    int*   srcSorted = (int*)  alloc((size_t)E * 4);
    unsigned short* g1 = (unsigned short*)alloc((size_t)N * FDIM * 2);  // bf16
    float* x2        = (float*)alloc((size_t)N * FDIM * 4);
    int*   pairs     = (int*)x2;        // alias: pairs dead before x2 written
    unsigned short* g2 = g1;            // g1 dead after first aggregate

    const int gT = (N + 127) / 128;   // 782 GEMM tiles (128 rows each)

    bucket_hist   <<<B0, 256, 0, stream>>>(dstIdx, E, B1, chunk, B0, H);
    scanA         <<<nSB, 256, 0, stream>>>(H, S, blockSums);
    scanB         <<<1, 512, 0, stream>>>(blockSums, nSB);
    scanC         <<<nSB, 256, 0, stream>>>(H, S, blockSums);
    bucket_scatter<<<B0, 256, 0, stream>>>(srcIdx, dstIdx, E, B1, chunk, B0, H, pairs);
    bucket_csr    <<<B1, 256, 0, stream>>>(pairs, H, B0, E, N, dinv, rowStart, srcSorted);

    gemm_scale<128><<<gT, 256, 0, stream>>>(x,  W1, dinv, g1, N);
    aggregate      <<<2048, 256, 0, stream>>>((const unsigned int*)g1, rowStart, srcSorted, dinv, b1, x2, N, 1);
    gemm_scale<64> <<<gT, 256, 0, stream>>>(x2, W2, dinv, g2, N);
    aggregate      <<<2048, 256, 0, stream>>>((const unsigned int*)g2, rowStart, srcSorted, dinv, b2, out, N, 0);
}

// Round 14
// 204.854 us; speedup vs baseline: 2.0907x; 2.0907x over previous
//
#include <hip/hip_runtime.h>
#include <hip/hip_bf16.h>

// 2-layer GCN on MI355X.
// out[v] = dinv[v] * ( sum_{e: dst=v} g[src_e] + g[v] ) + b,  g = (x@W) * dinv[row]
// dinv[v] = rsqrt(indeg(v) + 1)
// CSR build = bucketed counting sort, ALL atomics in LDS (no device atomics).
// g1/g2 stored BF16. aggregate: r9 version (best measured, 42 us).
// GEMM r14: W in LDS as BF16 (halves LDS + staging), 2 rows x 8 cols per
// thread, 64-row blocks -> grid 1563 = 76% wave capacity (r13 lesson: the
// 782-block grid capped occupancy at 38%; depth-4 reg queue spilled at VGPR 84).

#define FDIM 64    // HID_DIM == OUT_DIM
#define NPB  128   // nodes per bucket (dst >> 7)
#define MAXB1 800  // >= ceil(100000/128)=782

// bf16 helpers (bit-level; finite data only)
static __device__ __forceinline__ unsigned short f2bf(float f) {
    unsigned int u = __float_as_uint(f);
    unsigned int r = 0x7FFFu + ((u >> 16) & 1u);
    return (unsigned short)((u + r) >> 16);
}
static __device__ __forceinline__ float lof(unsigned int u) {   // low bf16 -> f32
    return __uint_as_float(u << 16);
}
static __device__ __forceinline__ float hif(unsigned int u) {   // high bf16 -> f32
    return __uint_as_float(u & 0xFFFF0000u);
}

// ---------------- phase 1a: per-block bucket histogram ----------------
__global__ __launch_bounds__(256) void bucket_hist(const int* __restrict__ dst, int E,
                                                   int B1, int chunk, int B0,
                                                   int* __restrict__ H) {
    __shared__ int hist[MAXB1];
    const int blk = blockIdx.x, t = threadIdx.x;
    for (int i = t; i < B1; i += 256) hist[i] = 0;
    __syncthreads();
    const int beg = blk * chunk, end = min(E, beg + chunk);
    for (int e = beg + t; e < end; e += 256) atomicAdd(&hist[dst[e] >> 7], 1);
    __syncthreads();
    for (int i = t; i < B1; i += 256) H[i * B0 + blk] = hist[i];  // bin-major
}

// ---------------- scan A: per-block sums over spans of 2048 ----------------
__global__ __launch_bounds__(256) void scanA(const int* __restrict__ a, int S,
                                             int* __restrict__ bs) {
    __shared__ int s[256];
    const int blk = blockIdx.x, t = threadIdx.x;
    const int base = blk * 2048 + t * 8;
    int sum = 0;
    #pragma unroll
    for (int j = 0; j < 8; ++j) { int idx = base + j; if (idx < S) sum += a[idx]; }
    s[t] = sum;
    __syncthreads();
    for (int off = 128; off > 0; off >>= 1) {
        if (t < off) s[t] += s[t + off];
        __syncthreads();
    }
    if (t == 0) bs[blk] = s[0];
}

// ---------------- scan B: exclusive scan of block sums (nB <= 512) ----------
__global__ __launch_bounds__(512) void scanB(int* __restrict__ bs, int nB) {
    __shared__ int s[512];
    const int t = threadIdx.x;
    int v = (t < nB) ? bs[t] : 0;
    s[t] = v;
    __syncthreads();
    for (int off = 1; off < 512; off <<= 1) {
        int x = s[t];
        int y = (t >= off) ? s[t - off] : 0;
        __syncthreads();
        s[t] = x + y;
        __syncthreads();
    }
    if (t < nB) bs[t] = s[t] - v;
}

// ---------------- scan C: in-place exclusive scan (span 2048/block) ---------
__global__ __launch_bounds__(256) void scanC(int* __restrict__ a, int S,
                                             const int* __restrict__ bs) {
    __shared__ int s[256];
    const int blk = blockIdx.x, t = threadIdx.x;
    const int base = blk * 2048 + t * 8;
    int v[8];
    int sum = 0;
    #pragma unroll
    for (int j = 0; j < 8; ++j) { int idx = base + j; v[j] = (idx < S) ? a[idx] : 0; sum += v[j]; }
    s[t] = sum;
    __syncthreads();
    const int own = sum;
    for (int off = 1; off < 256; off <<= 1) {
        int x = s[t];
        int y = (t >= off) ? s[t - off] : 0;
        __syncthreads();
        s[t] = x + y;
        __syncthreads();
    }
    int run = bs[blk] + s[t] - own;   // exclusive prefix for this thread's segment
    #pragma unroll
    for (int j = 0; j < 8; ++j) { int idx = base + j; if (idx < S) a[idx] = run; run += v[j]; }
}

// ------- phase 1b: scatter edges into bucket-grouped packed (dlow7,src) -----
__global__ __launch_bounds__(256) void bucket_scatter(const int* __restrict__ src,
                                                      const int* __restrict__ dst,
                                                      int E, int B1, int chunk, int B0,
                                                      const int* __restrict__ Hs,
                                                      int* __restrict__ pairs) {
    __shared__ int cur[MAXB1];
    const int blk = blockIdx.x, t = threadIdx.x;
    for (int i = t; i < B1; i += 256) cur[i] = Hs[i * B0 + blk];
    __syncthreads();
    const int beg = blk * chunk, end = min(E, beg + chunk);
    for (int e = beg + t; e < end; e += 256) {
        int d = dst[e];
        int pos = atomicAdd(&cur[d >> 7], 1);          // LDS atomic
        pairs[pos] = ((d & 127) << 17) | src[e];       // src < 2^17
    }
}

// ---------------- phase 2: per-bucket local counting sort -> CSR ------------
__global__ __launch_bounds__(256) void bucket_csr(const int* __restrict__ pairs,
                                                  const int* __restrict__ Hs,
                                                  int B0, int E, int N,
                                                  float* __restrict__ dinv,
                                                  int* __restrict__ rowStart,
                                                  int* __restrict__ srcSorted) {
    __shared__ int hist[NPB], pref[NPB], cur[NPB];
    const int b = blockIdx.x, t = threadIdx.x;
    const int B1 = gridDim.x;
    const int vbase = b * NPB;
    const int nv = min(NPB, N - vbase);
    const int estart = Hs[b * B0];
    const int eend = (b + 1 < B1) ? Hs[(b + 1) * B0] : E;

    if (t < NPB) hist[t] = 0;
    __syncthreads();
    for (int e = estart + t; e < eend; e += 256)
        atomicAdd(&hist[pairs[e] >> 17], 1);
    __syncthreads();

    if (t < NPB) pref[t] = hist[t];
    __syncthreads();
    for (int off = 1; off < NPB; off <<= 1) {
        int v = 0;
        if (t < NPB && t >= off) v = pref[t - off];
        __syncthreads();
        if (t < NPB) pref[t] += v;
        __syncthreads();
    }
    if (t < nv) {
        int ex = pref[t] - hist[t];          // exclusive prefix
        rowStart[vbase + t] = estart + ex;
        dinv[vbase + t] = rsqrtf((float)(hist[t] + 1));
        cur[t] = estart + ex;
    }
    if (b == B1 - 1 && t == 0) rowStart[N] = E;
    __syncthreads();
    for (int e = estart + t; e < eend; e += 256) {
        int p = pairs[e];
        int pos = atomicAdd(&cur[p >> 17], 1);       // LDS atomic
        srcSorted[pos] = p & 0x1FFFF;
    }
}

// ------- GEMM: W in LDS as BF16, 2 rows x 8 cols per thread -----------------
// Block = 256 threads, 64 rows/block -> grid 1563 (76% wave capacity).
// Thread t: cq=t&7 (cols 8cq..8cq+7), rg=t>>3 (rows 2rg..2rg+1).
// Per k: one uint4 LDS read (8 bf16 W) -> 16 FMAs (1 B/FMA incl. bf16 pack).
// W bf16 error ~1e-3 at output (budget 1.1e-2, current 2e-3).
template <int K>
__global__ __launch_bounds__(256, 8) void gemm_scale(const float* __restrict__ X,
                                                     const float* __restrict__ W,
                                                     const float* __restrict__ dinv,
                                                     unsigned short* __restrict__ G, int N) {
    __shared__ unsigned int Wl[K * FDIM / 2];      // bf16 col-pairs, row-major
    const int t = threadIdx.x;
    {
        const float4* Wv = reinterpret_cast<const float4*>(W);
        uint2* Wp = reinterpret_cast<uint2*>(Wl);
        #pragma unroll
        for (int i = 0; i < (K * FDIM) / (256 * 4); ++i) {
            float4 w = Wv[i * 256 + t];
            Wp[i * 256 + t] = make_uint2(
                (unsigned)f2bf(w.x) | ((unsigned)f2bf(w.y) << 16),
                (unsigned)f2bf(w.z) | ((unsigned)f2bf(w.w) << 16));
        }
    }
    __syncthreads();

    const int cq = t & 7;                    // col-group: cols 8cq..8cq+7
    const int rg = t >> 3;                   // row-group: rows 2rg..2rg+1
    const int r0 = blockIdx.x * 64 + rg * 2;
    if (r0 >= N) return;                     // no barriers below

    const int rA = r0;
    const int rB = min(r0 + 1, N - 1);
    const float4* xrA = reinterpret_cast<const float4*>(X + (size_t)rA * K);
    const float4* xrB = reinterpret_cast<const float4*>(X + (size_t)rB * K);
    const uint4* Wl4 = reinterpret_cast<const uint4*>(Wl);   // row k = 8 uint4

    float acc[2][8];
    #pragma unroll
    for (int i = 0; i < 2; ++i)
        #pragma unroll
        for (int c = 0; c < 8; ++c) acc[i][c] = 0.f;

    #pragma unroll 2
    for (int k4 = 0; k4 < K / 4; ++k4) {
        float4 xv0 = xrA[k4], xv1 = xrB[k4];
        float xs0[4] = {xv0.x, xv0.y, xv0.z, xv0.w};
        float xs1[4] = {xv1.x, xv1.y, xv1.z, xv1.w};
        #pragma unroll
        for (int j = 0; j < 4; ++j) {
            uint4 wp = Wl4[(4 * k4 + j) * 8 + cq];
            float wv[8] = {lof(wp.x), hif(wp.x), lof(wp.y), hif(wp.y),
                           lof(wp.z), hif(wp.z), lof(wp.w), hif(wp.w)};
            #pragma unroll
            for (int c = 0; c < 8; ++c) {
                acc[0][c] += xs0[j] * wv[c];
                acc[1][c] += xs1[j] * wv[c];
            }
        }
    }

    #pragma unroll
    for (int i = 0; i < 2; ++i) {
        const int r = r0 + i;
        if (r < N) {
            const float dv = dinv[r];
            unsigned int p0 = f2bf(acc[i][0] * dv) | ((unsigned)f2bf(acc[i][1] * dv) << 16);
            unsigned int p1 = f2bf(acc[i][2] * dv) | ((unsigned)f2bf(acc[i][3] * dv) << 16);
            unsigned int p2 = f2bf(acc[i][4] * dv) | ((unsigned)f2bf(acc[i][5] * dv) << 16);
            unsigned int p3 = f2bf(acc[i][6] * dv) | ((unsigned)f2bf(acc[i][7] * dv) << 16);
            *reinterpret_cast<uint4*>(G + (size_t)r * FDIM + cq * 8) = make_uint4(p0, p1, p2, p3);
        }
    }
}

// ------- aggregate (r9 version, 42 us): wave/node, half-wave pair-gather,
// 16-deep chained pipeline + binary tail --------------------------------------
#define GATHER2(ii, uu, off)  int ii = srcSorted[eb + 2*(off)]; \
                              unsigned int uu = Gu[(size_t)ii * 32 + fl];

__global__ __launch_bounds__(256, 4) void aggregate(const unsigned int* __restrict__ Gu,
                                                    const int* __restrict__ rowStart,
                                                    const int* __restrict__ srcSorted,
                                                    const float* __restrict__ dinv,
                                                    const float* __restrict__ bias,
                                                    float* __restrict__ OUT, int N, int doRelu) {
    const int lane   = threadIdx.x & 63;
    const int half   = lane >> 5;        // 0: even edges, 1: odd edges
    const int fl     = lane & 31;        // uint index within row (features 2fl,2fl+1)
    const int waveId = blockIdx.x * (blockDim.x >> 6) + (threadIdx.x >> 6);
    const int nWaves = gridDim.x * (blockDim.x >> 6);
    const float2 bv  = reinterpret_cast<const float2*>(bias)[fl];

    for (int v = waveId; v < N; v += nWaves) {
        const int beg = rowStart[v];
        const int end = rowStart[v + 1];

        unsigned int su = 0;
        if (half == 0) su = Gu[(size_t)v * 32 + fl];
        float ax = lof(su), ay = hif(su);

        int e = beg;
        for (; e + 16 <= end; e += 16) {
            const int eb = e + half;
            GATHER2(i0, u0, 0) GATHER2(i1, u1, 1) GATHER2(i2, u2, 2) GATHER2(i3, u3, 3)
            GATHER2(i4, u4, 4) GATHER2(i5, u5, 5) GATHER2(i6, u6, 6) GATHER2(i7, u7, 7)
            ax += ((lof(u0) + lof(u1)) + (lof(u2) + lof(u3)))
                + ((lof(u4) + lof(u5)) + (lof(u6) + lof(u7)));
            ay += ((hif(u0) + hif(u1)) + (hif(u2) + hif(u3)))
                + ((hif(u4) + hif(u5)) + (hif(u6) + hif(u7)));
        }
        int rem = end - e;
        if (rem >= 8) {
            const int eb = e + half;
            GATHER2(i0, u0, 0) GATHER2(i1, u1, 1) GATHER2(i2, u2, 2) GATHER2(i3, u3, 3)
            ax += (lof(u0) + lof(u1)) + (lof(u2) + lof(u3));
            ay += (hif(u0) + hif(u1)) + (hif(u2) + hif(u3));
            e += 8; rem -= 8;
        }
        if (rem >= 4) {
            const int eb = e + half;
            GATHER2(i0, u0, 0) GATHER2(i1, u1, 1)
            ax += lof(u0) + lof(u1);
            ay += hif(u0) + hif(u1);
            e += 4; rem -= 4;
        }
        if (rem >= 2) {
            const int eb = e + half;
            GATHER2(i0, u0, 0)
            ax += lof(u0);
            ay += hif(u0);
            e += 2; rem -= 2;
        }
        if (rem) {
            int i0 = srcSorted[e];
            unsigned int u0 = 0;
            if (half == 0) u0 = Gu[(size_t)i0 * 32 + fl];
            ax += lof(u0);
            ay += hif(u0);
        }

        ax += __shfl_xor(ax, 32, 64);
        ay += __shfl_xor(ay, 32, 64);

        const float dv = dinv[v];
        float2 r;
        r.x = ax * dv + bv.x;
        r.y = ay * dv + bv.y;
        if (doRelu) { r.x = fmaxf(r.x, 0.f); r.y = fmaxf(r.y, 0.f); }
        if (half == 0)
            reinterpret_cast<float2*>(OUT + (size_t)v * FDIM)[fl] = r;
    }
}

extern "C" void kernel_launch(void* const* d_in, const int* in_sizes, int n_in,
                              void* d_out, int out_size, void* d_ws, size_t ws_size,
                              hipStream_t stream) {
    const float* x     = (const float*)d_in[0];
    const int*   edges = (const int*)d_in[1];   // int32 per harness contract
    const float* W1    = (const float*)d_in[2];
    const float* b1    = (const float*)d_in[3];
    const float* W2    = (const float*)d_in[4];
    const float* b2    = (const float*)d_in[5];
    float*       out   = (float*)d_out;

    const int N = in_sizes[0] / 128;   // 100000
    const int E = in_sizes[1] / 2;     // 1600000
    const int* srcIdx = edges;
    const int* dstIdx = edges + E;

    const int B1 = (N + NPB - 1) / NPB;         // 782 buckets
    const int B0 = 256;                          // phase-1 blocks
    const int chunk = (E + B0 - 1) / B0;         // 6250
    const int S  = B1 * B0;                      // scanned size (200192)
    const int nSB = (S + 2047) / 2048;           // 98 scan blocks (<=512)

    // workspace layout (256B aligned slices)
    char* ws = (char*)d_ws;
    size_t off = 0;
    auto alloc = [&](size_t bytes) { char* p = ws + off; off = (off + bytes + 255) & ~(size_t)255; return p; };
    float* dinv      = (float*)alloc((size_t)N * 4);
    int*   H         = (int*)  alloc((size_t)S * 4);
    int*   blockSums = (int*)  alloc(512 * 4);
    int*   rowStart  = (int*)  alloc((size_t)(N + 1) * 4);
    int*   srcSorted = (int*)  alloc((size_t)E * 4);
    unsigned short* g1 = (unsigned short*)alloc((size_t)N * FDIM * 2);  // bf16
    float* x2        = (float*)alloc((size_t)N * FDIM * 4);
    int*   pairs     = (int*)x2;        // alias: pairs dead before x2 written
    unsigned short* g2 = g1;            // g1 dead after first aggregate

    const int gT = (N + 63) / 64;   // 1563 GEMM tiles (64 rows each)

    bucket_hist   <<<B0, 256, 0, stream>>>(dstIdx, E, B1, chunk, B0, H);
    scanA         <<<nSB, 256, 0, stream>>>(H, S, blockSums);
    scanB         <<<1, 512, 0, stream>>>(blockSums, nSB);
    scanC         <<<nSB, 256, 0, stream>>>(H, S, blockSums);
    bucket_scatter<<<B0, 256, 0, stream>>>(srcIdx, dstIdx, E, B1, chunk, B0, H, pairs);
    bucket_csr    <<<B1, 256, 0, stream>>>(pairs, H, B0, E, N, dinv, rowStart, srcSorted);

    gemm_scale<128><<<gT, 256, 0, stream>>>(x,  W1, dinv, g1, N);
    aggregate      <<<2048, 256, 0, stream>>>((const unsigned int*)g1, rowStart, srcSorted, dinv, b1, x2, N, 1);
    gemm_scale<64> <<<gT, 256, 0, stream>>>(x2, W2, dinv, g2, N);
    aggregate      <<<2048, 256, 0, stream>>>((const unsigned int*)g2, rowStart, srcSorted, dinv, b2, out, N, 0);
}

// Round 15
// 193.819 us; speedup vs baseline: 2.2097x; 1.0569x over previous
//
#include <hip/hip_runtime.h>
#include <hip/hip_bf16.h>

// 2-layer GCN on MI355X.
// out[v] = dinv[v] * ( sum_{e: dst=v} g[src_e] + g[v] ) + b,  g = (x@W) * dinv[row]
// dinv[v] = rsqrt(indeg(v) + 1)
// CSR build = bucketed counting sort, ALL atomics in LDS (no device atomics).
// g1/g2 stored BF16. aggregate: r9 version (best measured, 42 us).
// GEMM r15: X staged in LDS TRANSPOSED (Xt[k][row]) + W in LDS bf16; inner
// loop is pure LDS+VALU (r8/r9/r13/r14 lesson: any in-loop global X load is
// latency-bound at 40-56 us vs the ~16 us VALU wall; per-thread load chains
// don't batch without spilling). Xt reads: ds_read_b64, 2-way alias = free.

#define FDIM 64    // HID_DIM == OUT_DIM
#define NPB  128   // nodes per bucket (dst >> 7)
#define MAXB1 800  // >= ceil(100000/128)=782

// bf16 helpers (bit-level; finite data only)
static __device__ __forceinline__ unsigned short f2bf(float f) {
    unsigned int u = __float_as_uint(f);
    unsigned int r = 0x7FFFu + ((u >> 16) & 1u);
    return (unsigned short)((u + r) >> 16);
}
static __device__ __forceinline__ float lof(unsigned int u) {   // low bf16 -> f32
    return __uint_as_float(u << 16);
}
static __device__ __forceinline__ float hif(unsigned int u) {   // high bf16 -> f32
    return __uint_as_float(u & 0xFFFF0000u);
}

// ---------------- phase 1a: per-block bucket histogram ----------------
__global__ __launch_bounds__(256) void bucket_hist(const int* __restrict__ dst, int E,
                                                   int B1, int chunk, int B0,
                                                   int* __restrict__ H) {
    __shared__ int hist[MAXB1];
    const int blk = blockIdx.x, t = threadIdx.x;
    for (int i = t; i < B1; i += 256) hist[i] = 0;
    __syncthreads();
    const int beg = blk * chunk, end = min(E, beg + chunk);
    for (int e = beg + t; e < end; e += 256) atomicAdd(&hist[dst[e] >> 7], 1);
    __syncthreads();
    for (int i = t; i < B1; i += 256) H[i * B0 + blk] = hist[i];  // bin-major
}

// ---------------- scan A: per-block sums over spans of 2048 ----------------
__global__ __launch_bounds__(256) void scanA(const int* __restrict__ a, int S,
                                             int* __restrict__ bs) {
    __shared__ int s[256];
    const int blk = blockIdx.x, t = threadIdx.x;
    const int base = blk * 2048 + t * 8;
    int sum = 0;
    #pragma unroll
    for (int j = 0; j < 8; ++j) { int idx = base + j; if (idx < S) sum += a[idx]; }
    s[t] = sum;
    __syncthreads();
    for (int off = 128; off > 0; off >>= 1) {
        if (t < off) s[t] += s[t + off];
        __syncthreads();
    }
    if (t == 0) bs[blk] = s[0];
}

// ---------------- scan B: exclusive scan of block sums (nB <= 512) ----------
__global__ __launch_bounds__(512) void scanB(int* __restrict__ bs, int nB) {
    __shared__ int s[512];
    const int t = threadIdx.x;
    int v = (t < nB) ? bs[t] : 0;
    s[t] = v;
    __syncthreads();
    for (int off = 1; off < 512; off <<= 1) {
        int x = s[t];
        int y = (t >= off) ? s[t - off] : 0;
        __syncthreads();
        s[t] = x + y;
        __syncthreads();
    }
    if (t < nB) bs[t] = s[t] - v;
}

// ---------------- scan C: in-place exclusive scan (span 2048/block) ---------
__global__ __launch_bounds__(256) void scanC(int* __restrict__ a, int S,
                                             const int* __restrict__ bs) {
    __shared__ int s[256];
    const int blk = blockIdx.x, t = threadIdx.x;
    const int base = blk * 2048 + t * 8;
    int v[8];
    int sum = 0;
    #pragma unroll
    for (int j = 0; j < 8; ++j) { int idx = base + j; v[j] = (idx < S) ? a[idx] : 0; sum += v[j]; }
    s[t] = sum;
    __syncthreads();
    const int own = sum;
    for (int off = 1; off < 256; off <<= 1) {
        int x = s[t];
        int y = (t >= off) ? s[t - off] : 0;
        __syncthreads();
        s[t] = x + y;
        __syncthreads();
    }
    int run = bs[blk] + s[t] - own;   // exclusive prefix for this thread's segment
    #pragma unroll
    for (int j = 0; j < 8; ++j) { int idx = base + j; if (idx < S) a[idx] = run; run += v[j]; }
}

// ------- phase 1b: scatter edges into bucket-grouped packed (dlow7,src) -----
__global__ __launch_bounds__(256) void bucket_scatter(const int* __restrict__ src,
                                                      const int* __restrict__ dst,
                                                      int E, int B1, int chunk, int B0,
                                                      const int* __restrict__ Hs,
                                                      int* __restrict__ pairs) {
    __shared__ int cur[MAXB1];
    const int blk = blockIdx.x, t = threadIdx.x;
    for (int i = t; i < B1; i += 256) cur[i] = Hs[i * B0 + blk];
    __syncthreads();
    const int beg = blk * chunk, end = min(E, beg + chunk);
    for (int e = beg + t; e < end; e += 256) {
        int d = dst[e];
        int pos = atomicAdd(&cur[d >> 7], 1);          // LDS atomic
        pairs[pos] = ((d & 127) << 17) | src[e];       // src < 2^17
    }
}

// ---------------- phase 2: per-bucket local counting sort -> CSR ------------
__global__ __launch_bounds__(256) void bucket_csr(const int* __restrict__ pairs,
                                                  const int* __restrict__ Hs,
                                                  int B0, int E, int N,
                                                  float* __restrict__ dinv,
                                                  int* __restrict__ rowStart,
                                                  int* __restrict__ srcSorted) {
    __shared__ int hist[NPB], pref[NPB], cur[NPB];
    const int b = blockIdx.x, t = threadIdx.x;
    const int B1 = gridDim.x;
    const int vbase = b * NPB;
    const int nv = min(NPB, N - vbase);
    const int estart = Hs[b * B0];
    const int eend = (b + 1 < B1) ? Hs[(b + 1) * B0] : E;

    if (t < NPB) hist[t] = 0;
    __syncthreads();
    for (int e = estart + t; e < eend; e += 256)
        atomicAdd(&hist[pairs[e] >> 17], 1);
    __syncthreads();

    if (t < NPB) pref[t] = hist[t];
    __syncthreads();
    for (int off = 1; off < NPB; off <<= 1) {
        int v = 0;
        if (t < NPB && t >= off) v = pref[t - off];
        __syncthreads();
        if (t < NPB) pref[t] += v;
        __syncthreads();
    }
    if (t < nv) {
        int ex = pref[t] - hist[t];          // exclusive prefix
        rowStart[vbase + t] = estart + ex;
        dinv[vbase + t] = rsqrtf((float)(hist[t] + 1));
        cur[t] = estart + ex;
    }
    if (b == B1 - 1 && t == 0) rowStart[N] = E;
    __syncthreads();
    for (int e = estart + t; e < eend; e += 256) {
        int p = pairs[e];
        int pos = atomicAdd(&cur[p >> 17], 1);       // LDS atomic
        srcSorted[pos] = p & 0x1FFFF;
    }
}

// ------- GEMM: X transposed in LDS + W bf16 in LDS; pure LDS inner loop -----
// Block = 256 threads, 64 rows. Thread t: cq=t&7 (cols 8cq..8cq+7),
// rg=t>>3 (rows 2rg..2rg+1). Per k: ds_read_b64 (Xt, 2-way alias free) +
// ds_read_b128 (W bf16, broadcast) -> 8 unpack + 16 FMA. No global loads
// in the loop; staging = 4-8 independent float4 loads/thread, one barrier.
template <int K>
__global__ __launch_bounds__(256, 4) void gemm_scale(const float* __restrict__ X,
                                                     const float* __restrict__ W,
                                                     const float* __restrict__ dinv,
                                                     unsigned short* __restrict__ G, int N) {
    __shared__ float Xt[K * 64];                   // Xt[k*64 + row]
    __shared__ unsigned int Wl[K * FDIM / 2];      // bf16 col-pairs, row-major
    const int t = threadIdx.x;
    const int rowBase = blockIdx.x * 64;

    // ---- stage W -> LDS (bf16 pack) ----
    {
        const float4* Wv = reinterpret_cast<const float4*>(W);
        uint2* Wp = reinterpret_cast<uint2*>(Wl);
        #pragma unroll
        for (int i = 0; i < (K * FDIM) / (256 * 4); ++i) {
            float4 w = Wv[i * 256 + t];
            Wp[i * 256 + t] = make_uint2(
                (unsigned)f2bf(w.x) | ((unsigned)f2bf(w.y) << 16),
                (unsigned)f2bf(w.z) | ((unsigned)f2bf(w.w) << 16));
        }
    }
    // ---- stage X -> LDS transposed ----
    // thread t: row r=t&63, k-quarter q=t>>6 (K/4 k-values each).
    {
        const int r  = t & 63;
        const int q  = t >> 6;                     // 0..3
        const int rr = min(rowBase + r, N - 1);    // clamp (dup rows, discarded)
        const float4* xr = reinterpret_cast<const float4*>(X + (size_t)rr * K) + q * (K / 16);
        const int kq = q * (K / 4);
        #pragma unroll
        for (int i = 0; i < K / 16; i += 4) {      // 4 named float4 per round
            float4 a = xr[i + 0];
            float4 b = xr[i + 1];
            float4 c = xr[i + 2];
            float4 d = xr[i + 3];
            const int k0 = kq + i * 4;
            Xt[(k0 +  0) * 64 + r] = a.x;  Xt[(k0 +  1) * 64 + r] = a.y;
            Xt[(k0 +  2) * 64 + r] = a.z;  Xt[(k0 +  3) * 64 + r] = a.w;
            Xt[(k0 +  4) * 64 + r] = b.x;  Xt[(k0 +  5) * 64 + r] = b.y;
            Xt[(k0 +  6) * 64 + r] = b.z;  Xt[(k0 +  7) * 64 + r] = b.w;
            Xt[(k0 +  8) * 64 + r] = c.x;  Xt[(k0 +  9) * 64 + r] = c.y;
            Xt[(k0 + 10) * 64 + r] = c.z;  Xt[(k0 + 11) * 64 + r] = c.w;
            Xt[(k0 + 12) * 64 + r] = d.x;  Xt[(k0 + 13) * 64 + r] = d.y;
            Xt[(k0 + 14) * 64 + r] = d.z;  Xt[(k0 + 15) * 64 + r] = d.w;
        }
    }
    __syncthreads();

    const int cq = t & 7;                    // col-group: cols 8cq..8cq+7
    const int rg = t >> 3;                   // row-group: rows 2rg..2rg+1
    const int r0 = rowBase + rg * 2;
    if (r0 >= N) return;                     // no barriers below

    const uint4*  Wl4 = reinterpret_cast<const uint4*>(Wl);   // row k = 8 uint4
    const float2* Xt2 = reinterpret_cast<const float2*>(Xt);  // row k = 32 float2

    float acc[2][8];
    #pragma unroll
    for (int i = 0; i < 2; ++i)
        #pragma unroll
        for (int c = 0; c < 8; ++c) acc[i][c] = 0.f;

    #pragma unroll 4
    for (int k = 0; k < K; ++k) {
        float2 xv = Xt2[k * 32 + rg];        // x[2rg], x[2rg+1] at this k
        uint4  wp = Wl4[k * 8 + cq];         // 8 bf16 W cols
        float wv[8] = {lof(wp.x), hif(wp.x), lof(wp.y), hif(wp.y),
                       lof(wp.z), hif(wp.z), lof(wp.w), hif(wp.w)};
        #pragma unroll
        for (int c = 0; c < 8; ++c) {
            acc[0][c] += xv.x * wv[c];
            acc[1][c] += xv.y * wv[c];
        }
    }

    #pragma unroll
    for (int i = 0; i < 2; ++i) {
        const int r = r0 + i;
        if (r < N) {
            const float dv = dinv[r];
            unsigned int p0 = f2bf(acc[i][0] * dv) | ((unsigned)f2bf(acc[i][1] * dv) << 16);
            unsigned int p1 = f2bf(acc[i][2] * dv) | ((unsigned)f2bf(acc[i][3] * dv) << 16);
            unsigned int p2 = f2bf(acc[i][4] * dv) | ((unsigned)f2bf(acc[i][5] * dv) << 16);
            unsigned int p3 = f2bf(acc[i][6] * dv) | ((unsigned)f2bf(acc[i][7] * dv) << 16);
            *reinterpret_cast<uint4*>(G + (size_t)r * FDIM + cq * 8) = make_uint4(p0, p1, p2, p3);
        }
    }
}

// ------- aggregate (r9 version, 42 us): wave/node, half-wave pair-gather,
// 16-deep chained pipeline + binary tail --------------------------------------
#define GATHER2(ii, uu, off)  int ii = srcSorted[eb + 2*(off)]; \
                              unsigned int uu = Gu[(size_t)ii * 32 + fl];

__global__ __launch_bounds__(256, 4) void aggregate(const unsigned int* __restrict__ Gu,
                                                    const int* __restrict__ rowStart,
                                                    const int* __restrict__ srcSorted,
                                                    const float* __restrict__ dinv,
                                                    const float* __restrict__ bias,
                                                    float* __restrict__ OUT, int N, int doRelu) {
    const int lane   = threadIdx.x & 63;
    const int half   = lane >> 5;        // 0: even edges, 1: odd edges
    const int fl     = lane & 31;        // uint index within row (features 2fl,2fl+1)
    const int waveId = blockIdx.x * (blockDim.x >> 6) + (threadIdx.x >> 6);
    const int nWaves = gridDim.x * (blockDim.x >> 6);
    const float2 bv  = reinterpret_cast<const float2*>(bias)[fl];

    for (int v = waveId; v < N; v += nWaves) {
        const int beg = rowStart[v];
        const int end = rowStart[v + 1];

        unsigned int su = 0;
        if (half == 0) su = Gu[(size_t)v * 32 + fl];
        float ax = lof(su), ay = hif(su);

        int e = beg;
        for (; e + 16 <= end; e += 16) {
            const int eb = e + half;
            GATHER2(i0, u0, 0) GATHER2(i1, u1, 1) GATHER2(i2, u2, 2) GATHER2(i3, u3, 3)
            GATHER2(i4, u4, 4) GATHER2(i5, u5, 5) GATHER2(i6, u6, 6) GATHER2(i7, u7, 7)
            ax += ((lof(u0) + lof(u1)) + (lof(u2) + lof(u3)))
                + ((lof(u4) + lof(u5)) + (lof(u6) + lof(u7)));
            ay += ((hif(u0) + hif(u1)) + (hif(u2) + hif(u3)))
                + ((hif(u4) + hif(u5)) + (hif(u6) + hif(u7)));
        }
        int rem = end - e;
        if (rem >= 8) {
            const int eb = e + half;
            GATHER2(i0, u0, 0) GATHER2(i1, u1, 1) GATHER2(i2, u2, 2) GATHER2(i3, u3, 3)
            ax += (lof(u0) + lof(u1)) + (lof(u2) + lof(u3));
            ay += (hif(u0) + hif(u1)) + (hif(u2) + hif(u3));
            e += 8; rem -= 8;
        }
        if (rem >= 4) {
            const int eb = e + half;
            GATHER2(i0, u0, 0) GATHER2(i1, u1, 1)
            ax += lof(u0) + lof(u1);
            ay += hif(u0) + hif(u1);
            e += 4; rem -= 4;
        }
        if (rem >= 2) {
            const int eb = e + half;
            GATHER2(i0, u0, 0)
            ax += lof(u0);
            ay += hif(u0);
            e += 2; rem -= 2;
        }
        if (rem) {
            int i0 = srcSorted[e];
            unsigned int u0 = 0;
            if (half == 0) u0 = Gu[(size_t)i0 * 32 + fl];
            ax += lof(u0);
            ay += hif(u0);
        }

        ax += __shfl_xor(ax, 32, 64);
        ay += __shfl_xor(ay, 32, 64);

        const float dv = dinv[v];
        float2 r;
        r.x = ax * dv + bv.x;
        r.y = ay * dv + bv.y;
        if (doRelu) { r.x = fmaxf(r.x, 0.f); r.y = fmaxf(r.y, 0.f); }
        if (half == 0)
            reinterpret_cast<float2*>(OUT + (size_t)v * FDIM)[fl] = r;
    }
}

extern "C" void kernel_launch(void* const* d_in, const int* in_sizes, int n_in,
                              void* d_out, int out_size, void* d_ws, size_t ws_size,
                              hipStream_t stream) {
    const float* x     = (const float*)d_in[0];
    const int*   edges = (const int*)d_in[1];   // int32 per harness contract
    const float* W1    = (const float*)d_in[2];
    const float* b1    = (const float*)d_in[3];
    const float* W2    = (const float*)d_in[4];
    const float* b2    = (const float*)d_in[5];
    float*       out   = (float*)d_out;

    const int N = in_sizes[0] / 128;   // 100000
    const int E = in_sizes[1] / 2;     // 1600000
    const int* srcIdx = edges;
    const int* dstIdx = edges + E;

    const int B1 = (N + NPB - 1) / NPB;         // 782 buckets
    const int B0 = 256;                          // phase-1 blocks
    const int chunk = (E + B0 - 1) / B0;         // 6250
    const int S  = B1 * B0;                      // scanned size (200192)
    const int nSB = (S + 2047) / 2048;           // 98 scan blocks (<=512)

    // workspace layout (256B aligned slices)
    char* ws = (char*)d_ws;
    size_t off = 0;
    auto alloc = [&](size_t bytes) { char* p = ws + off; off = (off + bytes + 255) & ~(size_t)255; return p; };
    float* dinv      = (float*)alloc((size_t)N * 4);
    int*   H         = (int*)  alloc((size_t)S * 4);
    int*   blockSums = (int*)  alloc(512 * 4);
    int*   rowStart  = (int*)  alloc((size_t)(N + 1) * 4);
    int*   srcSorted = (int*)  alloc((size_t)E * 4);
    unsigned short* g1 = (unsigned short*)alloc((size_t)N * FDIM * 2);  // bf16
    float* x2        = (float*)alloc((size_t)N * FDIM * 4);
    int*   pairs     = (int*)x2;        // alias: pairs dead before x2 written
    unsigned short* g2 = g1;            // g1 dead after first aggregate

    const int gT = (N + 63) / 64;   // 1563 GEMM tiles (64 rows each)

    bucket_hist   <<<B0, 256, 0, stream>>>(dstIdx, E, B1, chunk, B0, H);
    scanA         <<<nSB, 256, 0, stream>>>(H, S, blockSums);
    scanB         <<<1, 512, 0, stream>>>(blockSums, nSB);
    scanC         <<<nSB, 256, 0, stream>>>(H, S, blockSums);
    bucket_scatter<<<B0, 256, 0, stream>>>(srcIdx, dstIdx, E, B1, chunk, B0, H, pairs);
    bucket_csr    <<<B1, 256, 0, stream>>>(pairs, H, B0, E, N, dinv, rowStart, srcSorted);

    gemm_scale<128><<<gT, 256, 0, stream>>>(x,  W1, dinv, g1, N);
    aggregate      <<<2048, 256, 0, stream>>>((const unsigned int*)g1, rowStart, srcSorted, dinv, b1, x2, N, 1);
    gemm_scale<64> <<<gT, 256, 0, stream>>>(x2, W2, dinv, g2, N);
    aggregate      <<<2048, 256, 0, stream>>>((const unsigned int*)g2, rowStart, srcSorted, dinv, b2, out, N, 0);
}

// Round 16
// 162.852 us; speedup vs baseline: 2.6299x; 1.1902x over previous
//
#include <hip/hip_runtime.h>
#include <hip/hip_bf16.h>

// 2-layer GCN on MI355X.
// out[v] = dinv[v] * ( sum_{e: dst=v} g[src_e] + g[v] ) + b,  g = (x@W) * dinv[row]
// dinv[v] = rsqrt(indeg(v) + 1)
// CSR build = bucketed counting sort, ALL atomics in LDS (no device atomics).
// g1/g2 stored BF16. aggregate: r9 version (best measured, 42 us).
// GEMM r16: MFMA 16x16x32 bf16 (Guideline 10). r8-r15 lesson: fp32 vector-FMA
// GEMM is stuck at 40-56 us vs 16 us VALU wall; MFMA makes compute ~1 us and
// leaves only the 51 MB X read (~10 us). Per wave: 16-row slab x 64 cols,
// W in registers (16 B-fragments), no LDS, no barriers. N=100000=6250 slabs.
// Layouts: A lane l -> row l&15, k = 32s+8*(l>>4)+j ; B lane l -> col l&15,
// same k ; C/D lane l reg i -> col l&15, row 4*(l>>4)+i [HW-verified m89].

#define FDIM 64    // HID_DIM == OUT_DIM
#define NPB  128   // nodes per bucket (dst >> 7)
#define MAXB1 800  // >= ceil(100000/128)=782

typedef __attribute__((ext_vector_type(8))) short bf16x8;   // MFMA A/B frag
typedef __attribute__((ext_vector_type(4))) float f32x4;    // MFMA C/D frag

// bf16 helpers (bit-level RTN; finite data only)
static __device__ __forceinline__ unsigned short f2bf(float f) {
    unsigned int u = __float_as_uint(f);
    unsigned int r = 0x7FFFu + ((u >> 16) & 1u);
    return (unsigned short)((u + r) >> 16);
}
static __device__ __forceinline__ float lof(unsigned int u) {   // low bf16 -> f32
    return __uint_as_float(u << 16);
}
static __device__ __forceinline__ float hif(unsigned int u) {   // high bf16 -> f32
    return __uint_as_float(u & 0xFFFF0000u);
}

// ---------------- phase 1a: per-block bucket histogram ----------------
__global__ __launch_bounds__(256) void bucket_hist(const int* __restrict__ dst, int E,
                                                   int B1, int chunk, int B0,
                                                   int* __restrict__ H) {
    __shared__ int hist[MAXB1];
    const int blk = blockIdx.x, t = threadIdx.x;
    for (int i = t; i < B1; i += 256) hist[i] = 0;
    __syncthreads();
    const int beg = blk * chunk, end = min(E, beg + chunk);
    for (int e = beg + t; e < end; e += 256) atomicAdd(&hist[dst[e] >> 7], 1);
    __syncthreads();
    for (int i = t; i < B1; i += 256) H[i * B0 + blk] = hist[i];  // bin-major
}

// ---------------- scan A: per-block sums over spans of 2048 ----------------
__global__ __launch_bounds__(256) void scanA(const int* __restrict__ a, int S,
                                             int* __restrict__ bs) {
    __shared__ int s[256];
    const int blk = blockIdx.x, t = threadIdx.x;
    const int base = blk * 2048 + t * 8;
    int sum = 0;
    #pragma unroll
    for (int j = 0; j < 8; ++j) { int idx = base + j; if (idx < S) sum += a[idx]; }
    s[t] = sum;
    __syncthreads();
    for (int off = 128; off > 0; off >>= 1) {
        if (t < off) s[t] += s[t + off];
        __syncthreads();
    }
    if (t == 0) bs[blk] = s[0];
}

// ---------------- scan B: exclusive scan of block sums (nB <= 512) ----------
__global__ __launch_bounds__(512) void scanB(int* __restrict__ bs, int nB) {
    __shared__ int s[512];
    const int t = threadIdx.x;
    int v = (t < nB) ? bs[t] : 0;
    s[t] = v;
    __syncthreads();
    for (int off = 1; off < 512; off <<= 1) {
        int x = s[t];
        int y = (t >= off) ? s[t - off] : 0;
        __syncthreads();
        s[t] = x + y;
        __syncthreads();
    }
    if (t < nB) bs[t] = s[t] - v;
}

// ---------------- scan C: in-place exclusive scan (span 2048/block) ---------
__global__ __launch_bounds__(256) void scanC(int* __restrict__ a, int S,
                                             const int* __restrict__ bs) {
    __shared__ int s[256];
    const int blk = blockIdx.x, t = threadIdx.x;
    const int base = blk * 2048 + t * 8;
    int v[8];
    int sum = 0;
    #pragma unroll
    for (int j = 0; j < 8; ++j) { int idx = base + j; v[j] = (idx < S) ? a[idx] : 0; sum += v[j]; }
    s[t] = sum;
    __syncthreads();
    const int own = sum;
    for (int off = 1; off < 256; off <<= 1) {
        int x = s[t];
        int y = (t >= off) ? s[t - off] : 0;
        __syncthreads();
        s[t] = x + y;
        __syncthreads();
    }
    int run = bs[blk] + s[t] - own;   // exclusive prefix for this thread's segment
    #pragma unroll
    for (int j = 0; j < 8; ++j) { int idx = base + j; if (idx < S) a[idx] = run; run += v[j]; }
}

// ------- phase 1b: scatter edges into bucket-grouped packed (dlow7,src) -----
__global__ __launch_bounds__(256) void bucket_scatter(const int* __restrict__ src,
                                                      const int* __restrict__ dst,
                                                      int E, int B1, int chunk, int B0,
                                                      const int* __restrict__ Hs,
                                                      int* __restrict__ pairs) {
    __shared__ int cur[MAXB1];
    const int blk = blockIdx.x, t = threadIdx.x;
    for (int i = t; i < B1; i += 256) cur[i] = Hs[i * B0 + blk];
    __syncthreads();
    const int beg = blk * chunk, end = min(E, beg + chunk);
    for (int e = beg + t; e < end; e += 256) {
        int d = dst[e];
        int pos = atomicAdd(&cur[d >> 7], 1);          // LDS atomic
        pairs[pos] = ((d & 127) << 17) | src[e];       // src < 2^17
    }
}

// ---------------- phase 2: per-bucket local counting sort -> CSR ------------
__global__ __launch_bounds__(256) void bucket_csr(const int* __restrict__ pairs,
                                                  const int* __restrict__ Hs,
                                                  int B0, int E, int N,
                                                  float* __restrict__ dinv,
                                                  int* __restrict__ rowStart,
                                                  int* __restrict__ srcSorted) {
    __shared__ int hist[NPB], pref[NPB], cur[NPB];
    const int b = blockIdx.x, t = threadIdx.x;
    const int B1 = gridDim.x;
    const int vbase = b * NPB;
    const int nv = min(NPB, N - vbase);
    const int estart = Hs[b * B0];
    const int eend = (b + 1 < B1) ? Hs[(b + 1) * B0] : E;

    if (t < NPB) hist[t] = 0;
    __syncthreads();
    for (int e = estart + t; e < eend; e += 256)
        atomicAdd(&hist[pairs[e] >> 17], 1);
    __syncthreads();

    if (t < NPB) pref[t] = hist[t];
    __syncthreads();
    for (int off = 1; off < NPB; off <<= 1) {
        int v = 0;
        if (t < NPB && t >= off) v = pref[t - off];
        __syncthreads();
        if (t < NPB) pref[t] += v;
        __syncthreads();
    }
    if (t < nv) {
        int ex = pref[t] - hist[t];          // exclusive prefix
        rowStart[vbase + t] = estart + ex;
        dinv[vbase + t] = rsqrtf((float)(hist[t] + 1));
        cur[t] = estart + ex;
    }
    if (b == B1 - 1 && t == 0) rowStart[N] = E;
    __syncthreads();
    for (int e = estart + t; e < eend; e += 256) {
        int p = pairs[e];
        int pos = atomicAdd(&cur[p >> 17], 1);       // LDS atomic
        srcSorted[pos] = p & 0x1FFFF;
    }
}

// ------- GEMM via MFMA 16x16x32 bf16: one 16-row slab per wave --------------
// g[row][col] = dinv[row] * sum_k X[row][k]*W[k][col], output packed bf16.
// B-fragments (W) register-resident per wave: bf[s][c], s=K/32, c=4 col-tiles.
// A-fragment per slab: af[s] from two aligned float4 global loads per lane.
template <int K>
__global__ __launch_bounds__(256, 2) void gemm_mfma(const float* __restrict__ X,
                                                    const float* __restrict__ W,
                                                    const float* __restrict__ dinv,
                                                    unsigned short* __restrict__ G, int N) {
    const int lane = threadIdx.x & 63;
    const int lr   = lane & 15;        // A-row / B-col / D-col within tile
    const int lg   = lane >> 4;        // k-group and D-row group
    const int wid  = (blockIdx.x * blockDim.x + threadIdx.x) >> 6;
    const int nW   = (gridDim.x * blockDim.x) >> 6;
    constexpr int NS = K / 32;

    // ---- W -> register B-fragments (L2-resident; once per wave) ----
    bf16x8 bf[NS][4];
    #pragma unroll
    for (int s = 0; s < NS; ++s) {
        #pragma unroll
        for (int c = 0; c < 4; ++c) {
            const float* wp = W + (size_t)(s * 32 + lg * 8) * FDIM + c * 16 + lr;
            bf16x8 v;
            #pragma unroll
            for (int j = 0; j < 8; ++j) v[j] = (short)f2bf(wp[(size_t)j * FDIM]);
            bf[s][c] = v;
        }
    }

    const int nSlab = N >> 4;          // N = 100000 -> 6250 slabs, no tail
    for (int sl = wid; sl < nSlab; sl += nW) {
        const int row0 = sl << 4;

        // A fragments: lane reads 32B chunks of row (row0+lr)
        bf16x8 af[NS];
        const float* xp = X + (size_t)(row0 + lr) * K + lg * 8;
        #pragma unroll
        for (int s = 0; s < NS; ++s) {
            float4 x0 = *reinterpret_cast<const float4*>(xp + s * 32);
            float4 x1 = *reinterpret_cast<const float4*>(xp + s * 32 + 4);
            bf16x8 v;
            v[0] = (short)f2bf(x0.x); v[1] = (short)f2bf(x0.y);
            v[2] = (short)f2bf(x0.z); v[3] = (short)f2bf(x0.w);
            v[4] = (short)f2bf(x1.x); v[5] = (short)f2bf(x1.y);
            v[6] = (short)f2bf(x1.z); v[7] = (short)f2bf(x1.w);
            af[s] = v;
        }

        f32x4 acc[4];
        #pragma unroll
        for (int c = 0; c < 4; ++c) acc[c] = (f32x4){0.f, 0.f, 0.f, 0.f};

        #pragma unroll
        for (int s = 0; s < NS; ++s) {
            #pragma unroll
            for (int c = 0; c < 4; ++c)
                acc[c] = __builtin_amdgcn_mfma_f32_16x16x32_bf16(af[s], bf[s][c], acc[c], 0, 0, 0);
        }

        // epilogue: lane l, reg i, tile c -> row=row0+4*lg+i, col=16c+lr
        const int rb = row0 + lg * 4;
        const float dv0 = dinv[rb + 0];
        const float dv1 = dinv[rb + 1];
        const float dv2 = dinv[rb + 2];
        const float dv3 = dinv[rb + 3];
        #pragma unroll
        for (int c = 0; c < 4; ++c) {
            unsigned short* gp = G + (size_t)rb * FDIM + c * 16 + lr;
            gp[0 * FDIM] = f2bf(acc[c][0] * dv0);
            gp[1 * FDIM] = f2bf(acc[c][1] * dv1);
            gp[2 * FDIM] = f2bf(acc[c][2] * dv2);
            gp[3 * FDIM] = f2bf(acc[c][3] * dv3);
        }
    }
}

// ------- aggregate (r9 version, 42 us): wave/node, half-wave pair-gather,
// 16-deep chained pipeline + binary tail --------------------------------------
#define GATHER2(ii, uu, off)  int ii = srcSorted[eb + 2*(off)]; \
                              unsigned int uu = Gu[(size_t)ii * 32 + fl];

__global__ __launch_bounds__(256, 4) void aggregate(const unsigned int* __restrict__ Gu,
                                                    const int* __restrict__ rowStart,
                                                    const int* __restrict__ srcSorted,
                                                    const float* __restrict__ dinv,
                                                    const float* __restrict__ bias,
                                                    float* __restrict__ OUT, int N, int doRelu) {
    const int lane   = threadIdx.x & 63;
    const int half   = lane >> 5;        // 0: even edges, 1: odd edges
    const int fl     = lane & 31;        // uint index within row (features 2fl,2fl+1)
    const int waveId = blockIdx.x * (blockDim.x >> 6) + (threadIdx.x >> 6);
    const int nWaves = gridDim.x * (blockDim.x >> 6);
    const float2 bv  = reinterpret_cast<const float2*>(bias)[fl];

    for (int v = waveId; v < N; v += nWaves) {
        const int beg = rowStart[v];
        const int end = rowStart[v + 1];

        unsigned int su = 0;
        if (half == 0) su = Gu[(size_t)v * 32 + fl];
        float ax = lof(su), ay = hif(su);

        int e = beg;
        for (; e + 16 <= end; e += 16) {
            const int eb = e + half;
            GATHER2(i0, u0, 0) GATHER2(i1, u1, 1) GATHER2(i2, u2, 2) GATHER2(i3, u3, 3)
            GATHER2(i4, u4, 4) GATHER2(i5, u5, 5) GATHER2(i6, u6, 6) GATHER2(i7, u7, 7)
            ax += ((lof(u0) + lof(u1)) + (lof(u2) + lof(u3)))
                + ((lof(u4) + lof(u5)) + (lof(u6) + lof(u7)));
            ay += ((hif(u0) + hif(u1)) + (hif(u2) + hif(u3)))
                + ((hif(u4) + hif(u5)) + (hif(u6) + hif(u7)));
        }
        int rem = end - e;
        if (rem >= 8) {
            const int eb = e + half;
            GATHER2(i0, u0, 0) GATHER2(i1, u1, 1) GATHER2(i2, u2, 2) GATHER2(i3, u3, 3)
            ax += (lof(u0) + lof(u1)) + (lof(u2) + lof(u3));
            ay += (hif(u0) + hif(u1)) + (hif(u2) + hif(u3));
            e += 8; rem -= 8;
        }
        if (rem >= 4) {
            const int eb = e + half;
            GATHER2(i0, u0, 0) GATHER2(i1, u1, 1)
            ax += lof(u0) + lof(u1);
            ay += hif(u0) + hif(u1);
            e += 4; rem -= 4;
        }
        if (rem >= 2) {
            const int eb = e + half;
            GATHER2(i0, u0, 0)
            ax += lof(u0);
            ay += hif(u0);
            e += 2; rem -= 2;
        }
        if (rem) {
            int i0 = srcSorted[e];
            unsigned int u0 = 0;
            if (half == 0) u0 = Gu[(size_t)i0 * 32 + fl];
            ax += lof(u0);
            ay += hif(u0);
        }

        ax += __shfl_xor(ax, 32, 64);
        ay += __shfl_xor(ay, 32, 64);

        const float dv = dinv[v];
        float2 r;
        r.x = ax * dv + bv.x;
        r.y = ay * dv + bv.y;
        if (doRelu) { r.x = fmaxf(r.x, 0.f); r.y = fmaxf(r.y, 0.f); }
        if (half == 0)
            reinterpret_cast<float2*>(OUT + (size_t)v * FDIM)[fl] = r;
    }
}

extern "C" void kernel_launch(void* const* d_in, const int* in_sizes, int n_in,
                              void* d_out, int out_size, void* d_ws, size_t ws_size,
                              hipStream_t stream) {
    const float* x     = (const float*)d_in[0];
    const int*   edges = (const int*)d_in[1];   // int32 per harness contract
    const float* W1    = (const float*)d_in[2];
    const float* b1    = (const float*)d_in[3];
    const float* W2    = (const float*)d_in[4];
    const float* b2    = (const float*)d_in[5];
    float*       out   = (float*)d_out;

    const int N = in_sizes[0] / 128;   // 100000
    const int E = in_sizes[1] / 2;     // 1600000
    const int* srcIdx = edges;
    const int* dstIdx = edges + E;

    const int B1 = (N + NPB - 1) / NPB;         // 782 buckets
    const int B0 = 256;                          // phase-1 blocks
    const int chunk = (E + B0 - 1) / B0;         // 6250
    const int S  = B1 * B0;                      // scanned size (200192)
    const int nSB = (S + 2047) / 2048;           // 98 scan blocks (<=512)

    // workspace layout (256B aligned slices)
    char* ws = (char*)d_ws;
    size_t off = 0;
    auto alloc = [&](size_t bytes) { char* p = ws + off; off = (off + bytes + 255) & ~(size_t)255; return p; };
    float* dinv      = (float*)alloc((size_t)N * 4);
    int*   H         = (int*)  alloc((size_t)S * 4);
    int*   blockSums = (int*)  alloc(512 * 4);
    int*   rowStart  = (int*)  alloc((size_t)(N + 1) * 4);
    int*   srcSorted = (int*)  alloc((size_t)E * 4);
    unsigned short* g1 = (unsigned short*)alloc((size_t)N * FDIM * 2);  // bf16
    float* x2        = (float*)alloc((size_t)N * FDIM * 4);
    int*   pairs     = (int*)x2;        // alias: pairs dead before x2 written
    unsigned short* g2 = g1;            // g1 dead after first aggregate

    bucket_hist   <<<B0, 256, 0, stream>>>(dstIdx, E, B1, chunk, B0, H);
    scanA         <<<nSB, 256, 0, stream>>>(H, S, blockSums);
    scanB         <<<1, 512, 0, stream>>>(blockSums, nSB);
    scanC         <<<nSB, 256, 0, stream>>>(H, S, blockSums);
    bucket_scatter<<<B0, 256, 0, stream>>>(srcIdx, dstIdx, E, B1, chunk, B0, H, pairs);
    bucket_csr    <<<B1, 256, 0, stream>>>(pairs, H, B0, E, N, dinv, rowStart, srcSorted);

    gemm_mfma<128><<<768, 256, 0, stream>>>(x,  W1, dinv, g1, N);
    aggregate     <<<2048, 256, 0, stream>>>((const unsigned int*)g1, rowStart, srcSorted, dinv, b1, x2, N, 1);
    gemm_mfma<64> <<<768, 256, 0, stream>>>(x2, W2, dinv, g2, N);
    aggregate     <<<2048, 256, 0, stream>>>((const unsigned int*)g2, rowStart, srcSorted, dinv, b2, out, N, 0);
}